// Round 1
// baseline (778.229 us; speedup 1.0000x reference)
//
#include <hip/hip_runtime.h>

#define B_ 4
#define S_ 2048
#define D_ 1024
#define M_ (B_*S_)           // 8192
#define K2_ 2048
#define N2_ 2048
#define NTOT (B_*S_*D_)      // 8388608
#define DD (D_*D_)           // 1048576

typedef __attribute__((ext_vector_type(4))) float f32x4;
typedef __attribute__((ext_vector_type(8))) short short8;
typedef __attribute__((ext_vector_type(4))) unsigned short u16x4;

static __device__ __forceinline__ unsigned short f2bf(float f) {
    union { float f; unsigned int u; } v; v.f = f;
    unsigned int u = v.u;
    unsigned int r = (u + 0x7fffu + ((u >> 16) & 1u)) >> 16;
    return (unsigned short)r;
}
static __device__ __forceinline__ float bf2f(unsigned short h) {
    union { unsigned int u; float f; } v; v.u = ((unsigned int)h) << 16;
    return v.f;
}

// ---------------------------------------------------------------------------
// Shared 128x128-tile bf16 MFMA GEMM core. A is [.,K] row-major (K-contig),
// B is given TRANSPOSED [N,K] row-major. K iterated in BK=64 chunks staged to
// LDS via global_load_lds width=16 (m97 structure).
// ---------------------------------------------------------------------------
__device__ __forceinline__ void mfma_gemm_128(const unsigned short* __restrict__ Ag, int astride,
                                              const unsigned short* __restrict__ Bg, int bstride,
                                              int kiters,
                                              unsigned short* As, unsigned short* Bs,
                                              f32x4 acc[4][4])
{
    const int tid  = threadIdx.x;
    const int wave = tid >> 6, lane = tid & 63;
    const int q    = lane >> 4, lm = lane & 15;
    const int wm   = (wave >> 1) * 64, wn = (wave & 1) * 64;
    const int crow = lane >> 3;          // 0..7 row within 8-row chunk
    const int ccol = (lane & 7) * 8;     // bf16 col offset within 64-wide tile

    for (int kt = 0; kt < kiters; ++kt) {
        const int k0 = kt * 64;
        __syncthreads();   // previous iter's LDS reads done before overwrite
#pragma unroll
        for (int i2 = 0; i2 < 4; ++i2) {
            int c   = i2 * 4 + wave;       // chunk 0..15, wave-uniform
            int row = c * 8 + crow;        // tile-local row 0..127
            const unsigned short* ga = Ag + (long)row * astride + k0 + ccol;
            const unsigned short* gb = Bg + (long)row * bstride + k0 + ccol;
            __builtin_amdgcn_global_load_lds((const __attribute__((address_space(1))) void*)ga,
                                             (__attribute__((address_space(3))) void*)(As + c * 512),
                                             16, 0, 0);
            __builtin_amdgcn_global_load_lds((const __attribute__((address_space(1))) void*)gb,
                                             (__attribute__((address_space(3))) void*)(Bs + c * 512),
                                             16, 0, 0);
        }
        __syncthreads();   // implies vmcnt(0) drain -> LDS data visible
#pragma unroll
        for (int kk = 0; kk < 64; kk += 32) {
            short8 a[4], b[4];
#pragma unroll
            for (int t = 0; t < 4; ++t) {
                a[t] = *(const short8*)(As + (wm + t * 16 + lm) * 64 + kk + q * 8);
                b[t] = *(const short8*)(Bs + (wn + t * 16 + lm) * 64 + kk + q * 8);
            }
#pragma unroll
            for (int um = 0; um < 4; ++um)
#pragma unroll
                for (int un = 0; un < 4; ++un)
                    acc[um][un] = __builtin_amdgcn_mfma_f32_16x16x32_bf16(a[um], b[un], acc[um][un], 0, 0, 0);
        }
    }
}

// ---------------------------------------------------------------------------
// Main mixing GEMM: C = A2 @ B2  (M=8192, N=K=2048), epilogue computes
// bd = C - psi, stores bf16, accumulates sum(bd^2) -> atomic.
// ---------------------------------------------------------------------------
__global__ __launch_bounds__(256) void gemm_main(const unsigned short* __restrict__ A2,
                                                 const unsigned short* __restrict__ B2T,
                                                 const float* __restrict__ psi_r,
                                                 const float* __restrict__ psi_i,
                                                 unsigned short* __restrict__ bd2,
                                                 float* __restrict__ sumsq)
{
    __shared__ unsigned short As[128 * 64];
    __shared__ unsigned short Bs[128 * 64];
    __shared__ float red[4];
    f32x4 acc[4][4];
#pragma unroll
    for (int i = 0; i < 4; ++i)
#pragma unroll
        for (int j = 0; j < 4; ++j) acc[i][j] = (f32x4)0.0f;

    const int nt = blockIdx.x, mt = blockIdx.y;
    mfma_gemm_128(A2 + (long)mt * 128 * K2_, K2_,
                  B2T + (long)nt * 128 * K2_, K2_, K2_ / 64, As, Bs, acc);

    const int tid = threadIdx.x, wave = tid >> 6, lane = tid & 63;
    const int q = lane >> 4, lm = lane & 15;
    const int wm = (wave >> 1) * 64, wn = (wave & 1) * 64;
    float ss = 0.f;
#pragma unroll
    for (int um = 0; um < 4; ++um) {
#pragma unroll
        for (int un = 0; un < 4; ++un) {
            int coln = nt * 128 + wn + un * 16 + lm;
#pragma unroll
            for (int i = 0; i < 4; ++i) {
                int rowm = mt * 128 + wm + um * 16 + q * 4 + i;
                float c = acc[um][un][i];
                float p = (coln < D_) ? psi_r[(long)rowm * D_ + coln]
                                      : psi_i[(long)rowm * D_ + (coln - D_)];
                float bd = c - p;
                bd2[(long)rowm * N2_ + coln] = f2bf(bd);
                ss += bd * bd;
            }
        }
    }
    for (int off = 32; off > 0; off >>= 1) ss += __shfl_down(ss, off);
    if (lane == 0) red[wave] = ss;
    __syncthreads();
    if (tid == 0) atomicAdd(sumsq, red[0] + red[1] + red[2] + red[3]);
}

// ---------------------------------------------------------------------------
// H GEMM: H[b] = magT[b] * magT[b]^T contraction over s:
// H[d,e] = (1/S) sum_s magT[d,s] magT[e,s]   (both operands from magT)
// ---------------------------------------------------------------------------
__global__ __launch_bounds__(256) void gemm_H(const unsigned short* __restrict__ magT,
                                              float* __restrict__ H)
{
    __shared__ unsigned short As[128 * 64];
    __shared__ unsigned short Bs[128 * 64];
    f32x4 acc[4][4];
#pragma unroll
    for (int i = 0; i < 4; ++i)
#pragma unroll
        for (int j = 0; j < 4; ++j) acc[i][j] = (f32x4)0.0f;

    const int b = blockIdx.z;
    const unsigned short* Mb = magT + (long)b * D_ * S_;
    mfma_gemm_128(Mb + (long)blockIdx.y * 128 * S_, S_,
                  Mb + (long)blockIdx.x * 128 * S_, S_, S_ / 64, As, Bs, acc);

    const int tid = threadIdx.x, wave = tid >> 6, lane = tid & 63;
    const int q = lane >> 4, lm = lane & 15;
    const int wm = (wave >> 1) * 64, wn = (wave & 1) * 64;
    const float inv_s = 1.0f / (float)S_;
#pragma unroll
    for (int um = 0; um < 4; ++um) {
#pragma unroll
        for (int un = 0; un < 4; ++un) {
            int coln = blockIdx.x * 128 + wn + un * 16 + lm;
#pragma unroll
            for (int i = 0; i < 4; ++i) {
                int rowm = blockIdx.y * 128 + wm + um * 16 + q * 4 + i;
                H[(long)b * DD + (long)rowm * D_ + coln] = acc[um][un][i] * inv_s;
            }
        }
    }
}

// psi <- x, A2 <- bf16 pack [psi_r | psi_i] along K
__global__ void init_kernel(const float* __restrict__ xr, const float* __restrict__ xi,
                            float* __restrict__ psi_r, float* __restrict__ psi_i,
                            unsigned short* __restrict__ A2)
{
    long t = (long)blockIdx.x * 256 + threadIdx.x;
    long i = t * 4;
    f32x4 r  = *(const f32x4*)(xr + i);
    f32x4 im = *(const f32x4*)(xi + i);
    *(f32x4*)(psi_r + i) = r;
    *(f32x4*)(psi_i + i) = im;
    long m = i / D_; int d = (int)(i % D_);
    u16x4 rr, ii;
#pragma unroll
    for (int j = 0; j < 4; ++j) { rr[j] = f2bf(r[j]); ii[j] = f2bf(im[j]); }
    *(u16x4*)(A2 + m * K2_ + d) = rr;
    *(u16x4*)(A2 + m * K2_ + D_ + d) = ii;
}

// B2T[n][k] = B2[k][n], B2 = [[Wr, Wi], [-Wi, Wr]]; LDS tile transpose
__global__ __launch_bounds__(256) void pack_b2t(const float* __restrict__ Wr,
                                                const float* __restrict__ Wi,
                                                unsigned short* __restrict__ B2T)
{
    __shared__ float T[64][65];
    int k0 = blockIdx.x * 64;
    int n0 = blockIdx.y * 64;
    int t = threadIdx.x;
#pragma unroll
    for (int it = 0; it < 16; ++it) {
        int idx = it * 256 + t;
        int kl = idx >> 6, nl = idx & 63;
        int k = k0 + kl, n = n0 + nl;
        float v;
        if (k < D_) v = (n < D_) ? Wr[k * D_ + n] : Wi[k * D_ + (n - D_)];
        else        v = (n < D_) ? -Wi[(k - D_) * D_ + n] : Wr[(k - D_) * D_ + (n - D_)];
        T[kl][nl] = v;
    }
    __syncthreads();
#pragma unroll
    for (int it = 0; it < 16; ++it) {
        int idx = it * 256 + t;
        int nl = idx >> 6, kl = idx & 63;
        B2T[(long)(n0 + nl) * K2_ + (k0 + kl)] = f2bf(T[kl][nl]);
    }
}

__global__ void damp_kernel(const float* __restrict__ Lops, float* __restrict__ dampv)
{
    int d = blockIdx.x * 256 + threadIdx.x;
    float s = 0.f;
#pragma unroll
    for (int k = 0; k < 4; ++k) { float v = Lops[k * D_ + d]; s += v * v; }
    dampv[d] = 1.0f - 0.01f * s;
}

__global__ void rms_kernel(const float* __restrict__ sumsq, float* __restrict__ rms)
{
    float mean = *sumsq / (float)NTOT;
    mean = fmaxf(mean, 1e-12f);
    *rms = fmaxf(sqrtf(mean), 1e-3f);
}

// magT[b][d][s] = |bd[b,s,d]| * dampv[d] / rms   (64x64 LDS tile transpose)
__global__ __launch_bounds__(256) void magt_kernel(const unsigned short* __restrict__ bd2,
                                                   const float* __restrict__ dampv,
                                                   const float* __restrict__ rms,
                                                   unsigned short* __restrict__ magT)
{
    __shared__ float T[64][65];
    const float inv = 1.0f / *rms;
    int m0 = blockIdx.x * 64;
    int d0 = blockIdx.y * 64;
    int t = threadIdx.x;
#pragma unroll
    for (int it = 0; it < 16; ++it) {
        int idx = it * 256 + t;
        int sl = idx >> 6, dl = idx & 63;
        long m = m0 + sl; int d = d0 + dl;
        float br = bf2f(bd2[m * N2_ + d]);
        float bi = bf2f(bd2[m * N2_ + D_ + d]);
        T[sl][dl] = sqrtf(br * br + bi * bi) * dampv[d] * inv;
    }
    __syncthreads();
    int b = m0 / S_;
    int s0 = m0 % S_;
#pragma unroll
    for (int it = 0; it < 16; ++it) {
        int idx = it * 256 + t;
        int dl = idx >> 6, sl = idx & 63;
        magT[(long)b * D_ * S_ + (long)(d0 + dl) * S_ + (s0 + sl)] = f2bf(T[sl][dl]);
    }
}

__global__ __launch_bounds__(256) void norms_kernel(const float* __restrict__ H,
                                                    const float* __restrict__ Hp,
                                                    float* __restrict__ diff2,
                                                    float* __restrict__ prev2)
{
    __shared__ float redd[4], redp[4];
    long t = (long)blockIdx.x * 256 + threadIdx.x;
    long i = t * 4;
    int b = (int)(i / DD);
    f32x4 h  = *(const f32x4*)(H + i);
    f32x4 hp = *(const f32x4*)(Hp + i);
    float d2 = 0.f, p2 = 0.f;
#pragma unroll
    for (int j = 0; j < 4; ++j) { float df = h[j] - hp[j]; d2 += df * df; p2 += hp[j] * hp[j]; }
    int lane = threadIdx.x & 63, wave = threadIdx.x >> 6;
    for (int off = 32; off > 0; off >>= 1) { d2 += __shfl_down(d2, off); p2 += __shfl_down(p2, off); }
    if (lane == 0) { redd[wave] = d2; redp[wave] = p2; }
    __syncthreads();
    if (threadIdx.x == 0) {
        atomicAdd(diff2 + b, redd[0] + redd[1] + redd[2] + redd[3]);
        atomicAdd(prev2 + b, redp[0] + redp[1] + redp[2] + redp[3]);
    }
}

__global__ void finalize_kernel(const float* __restrict__ H,
                                const float* __restrict__ diff2,
                                const float* __restrict__ prev2,
                                const float* __restrict__ theta,
                                const float* __restrict__ jscale,
                                const float* __restrict__ kappa,
                                int l,
                                float* __restrict__ factors)
{
    __shared__ float rmax[4], rmin[4];
    int b = blockIdx.x;
    int t = threadIdx.x;
    float mx = -1e30f, mn = 1e30f;
    for (int d = t; d < D_; d += 256) {
        float v = H[(long)b * DD + (long)d * D_ + d];
        mx = fmaxf(mx, v); mn = fminf(mn, v);
    }
    int lane = t & 63, wave = t >> 6;
    for (int off = 32; off > 0; off >>= 1) {
        mx = fmaxf(mx, __shfl_down(mx, off));
        mn = fminf(mn, __shfl_down(mn, off));
    }
    if (lane == 0) { rmax[wave] = mx; rmin[wave] = mn; }
    __syncthreads();
    if (t == 0) {
        mx = fmaxf(fmaxf(rmax[0], rmax[1]), fmaxf(rmax[2], rmax[3]));
        mn = fminf(fminf(rmin[0], rmin[1]), fminf(rmin[2], rmin[3]));
        float dn = sqrtf(diff2[b]);
        float pn = sqrtf(prev2[b]);
        float K = dn / (pn + 1e-6f);
        int jumped = K > kappa[l];
        float cond = mx / (mn + 1e-12f);
        int escaped = cond > 100.0f;
        float js = jumped ? jscale[l] : 1.0f;
        float th = theta[l];
        factors[2 * b]     = js * (escaped ? cosf(th) : 1.0f);
        factors[2 * b + 1] = js * (escaped ? sinf(th) : 0.0f);
    }
}

// psi += bd*(1-damp)*factor (complex); optionally re-pack A2 for next layer
__global__ void update_kernel(const unsigned short* __restrict__ bd2,
                              const float* __restrict__ dampv,
                              const float* __restrict__ factors,
                              float* __restrict__ psi_r,
                              float* __restrict__ psi_i,
                              unsigned short* __restrict__ A2,
                              int write_a2)
{
    long t = (long)blockIdx.x * 256 + threadIdx.x;
    long i = t * 4;
    long m = i / D_; int d = (int)(i % D_);
    int b = (int)(m / S_);
    float fr = factors[2 * b], fi = factors[2 * b + 1];
    u16x4 brv = *(const u16x4*)(bd2 + m * N2_ + d);
    u16x4 biv = *(const u16x4*)(bd2 + m * N2_ + D_ + d);
    f32x4 w  = *(const f32x4*)(dampv + d);
    f32x4 pr = *(const f32x4*)(psi_r + i);
    f32x4 pi = *(const f32x4*)(psi_i + i);
    u16x4 ar, ai;
#pragma unroll
    for (int j = 0; j < 4; ++j) {
        float br = bf2f(brv[j]) * w[j];
        float bi = bf2f(biv[j]) * w[j];
        float nr = pr[j] + br * fr - bi * fi;
        float ni = pi[j] + br * fi + bi * fr;
        pr[j] = nr; pi[j] = ni;
        ar[j] = f2bf(nr); ai[j] = f2bf(ni);
    }
    *(f32x4*)(psi_r + i) = pr;
    *(f32x4*)(psi_i + i) = pi;
    if (write_a2) {
        *(u16x4*)(A2 + m * K2_ + d) = ar;
        *(u16x4*)(A2 + m * K2_ + D_ + d) = ai;
    }
}

extern "C" void kernel_launch(void* const* d_in, const int* in_sizes, int n_in,
                              void* d_out, int out_size, void* d_ws, size_t ws_size,
                              hipStream_t stream)
{
    const float* xr     = (const float*)d_in[0];
    const float* xi     = (const float*)d_in[1];
    const float* Hprev  = (const float*)d_in[2];
    const float* Wr     = (const float*)d_in[3];
    const float* Wi     = (const float*)d_in[4];
    const float* Lops   = (const float*)d_in[5];
    const float* theta  = (const float*)d_in[6];
    const float* jscale = (const float*)d_in[7];
    const float* kappa  = (const float*)d_in[8];

    float* psi_r = (float*)d_out;           // [B,S,D] real plane of output
    float* psi_i = psi_r + NTOT;            // imag plane

    char* ws = (char*)d_ws;
    unsigned short* A2   = (unsigned short*)ws;               // 33554432 B
    unsigned short* magT = A2;                                // aliased (A2 dead when magT live)
    unsigned short* B2T  = (unsigned short*)(ws + 33554432);  // 8388608 B
    unsigned short* bd2  = (unsigned short*)(ws + 41943040);  // 33554432 B
    float* H0   = (float*)(ws + 75497472);                    // 16777216 B
    float* H1   = (float*)(ws + 92274688);                    // 16777216 B
    float* scal = (float*)(ws + 109051904);
    float* sumsq   = scal + 0;
    float* rms     = scal + 1;
    float* diff2   = scal + 2;   // [4]
    float* prev2   = scal + 6;   // [4]
    float* factors = scal + 10;  // [8]
    float* dampv   = scal + 18;  // [1024]

    init_kernel<<<NTOT / 4 / 256, 256, 0, stream>>>(xr, xi, psi_r, psi_i, A2);

    for (int l = 0; l < 2; ++l) {
        const float* Hp = (l == 0) ? Hprev : H0;
        float* Hc = (l == 0) ? H0 : H1;
        (void)hipMemsetAsync(scal, 0, 10 * sizeof(float), stream);
        pack_b2t<<<dim3(32, 32), 256, 0, stream>>>(Wr + (long)l * DD, Wi + (long)l * DD, B2T);
        damp_kernel<<<4, 256, 0, stream>>>(Lops + (long)l * 4 * D_, dampv);
        gemm_main<<<dim3(N2_ / 128, M_ / 128), 256, 0, stream>>>(A2, B2T, psi_r, psi_i, bd2, sumsq);
        rms_kernel<<<1, 1, 0, stream>>>(sumsq, rms);
        magt_kernel<<<dim3(M_ / 64, D_ / 64), 256, 0, stream>>>(bd2, dampv, rms, magT);
        gemm_H<<<dim3(D_ / 128, D_ / 128, B_), 256, 0, stream>>>(magT, Hc);
        norms_kernel<<<(B_ * DD) / 4 / 256, 256, 0, stream>>>(Hc, Hp, diff2, prev2);
        finalize_kernel<<<B_, 256, 0, stream>>>(Hc, diff2, prev2, theta, jscale, kappa, l, factors);
        update_kernel<<<NTOT / 4 / 256, 256, 0, stream>>>(bd2, dampv, factors, psi_r, psi_i, A2, l == 0);
    }
}

// Round 2
// 510.279 us; speedup vs baseline: 1.5251x; 1.5251x over previous
//
#include <hip/hip_runtime.h>

#define B_ 4
#define S_ 2048
#define D_ 1024
#define M_ (B_*S_)           // 8192
#define K2_ 2048
#define N2_ 2048
#define NTOT (B_*S_*D_)      // 8388608
#define DD (D_*D_)           // 1048576

typedef __attribute__((ext_vector_type(4))) float f32x4;
typedef __attribute__((ext_vector_type(8))) short short8;
typedef __attribute__((ext_vector_type(4))) unsigned short u16x4;

static __device__ __forceinline__ unsigned short f2bf(float f) {
    union { float f; unsigned int u; } v; v.f = f;
    unsigned int u = v.u;
    unsigned int r = (u + 0x7fffu + ((u >> 16) & 1u)) >> 16;
    return (unsigned short)r;
}
static __device__ __forceinline__ float bf2f(unsigned short h) {
    union { unsigned int u; float f; } v; v.u = ((unsigned int)h) << 16;
    return v.f;
}

// scal layout (fp32 slots): [0..1] sumsq[l], [2..9] diff2[l*4+b],
// [10..17] prev2[l*4+b], [18..25] diag-max bits, [26..33] diag-min bits,
// [64..2111] dampv[2][1024]

// ---------------------------------------------------------------------------
// 128x128-tile bf16 MFMA GEMM core, XOR-swizzled LDS to kill bank conflicts.
// LDS physical slot j of row r holds logical 16B-granule j^(r&7); the staging
// fetches the swizzled granule from global (per-lane source addr is free),
// the fragment reads apply the same XOR.
// ---------------------------------------------------------------------------
__device__ __forceinline__ void mfma_gemm_128(const unsigned short* __restrict__ Ag, long astride,
                                              const unsigned short* __restrict__ Bg, long bstride,
                                              int kiters,
                                              unsigned short* As, unsigned short* Bs,
                                              f32x4 acc[4][4])
{
    const int tid  = threadIdx.x;
    const int wave = tid >> 6, lane = tid & 63;
    const int q    = lane >> 4, lm = lane & 15;
    const int wm   = (wave >> 1) * 64, wn = (wave & 1) * 64;
    const int crow = lane >> 3;                       // 0..7 row within chunk
    const int gcol = ((lane & 7) ^ crow) * 8;         // swizzled source granule

    for (int kt = 0; kt < kiters; ++kt) {
        const long k0 = (long)kt * 64;
        __syncthreads();
#pragma unroll
        for (int i2 = 0; i2 < 4; ++i2) {
            int c   = i2 * 4 + wave;                  // chunk 0..15, wave-uniform
            int row = c * 8 + crow;                   // tile-local row
            const unsigned short* ga = Ag + (long)row * astride + k0 + gcol;
            const unsigned short* gb = Bg + (long)row * bstride + k0 + gcol;
            __builtin_amdgcn_global_load_lds((const __attribute__((address_space(1))) void*)ga,
                                             (__attribute__((address_space(3))) void*)(As + c * 512),
                                             16, 0, 0);
            __builtin_amdgcn_global_load_lds((const __attribute__((address_space(1))) void*)gb,
                                             (__attribute__((address_space(3))) void*)(Bs + c * 512),
                                             16, 0, 0);
        }
        __syncthreads();
#pragma unroll
        for (int kk = 0; kk < 64; kk += 32) {
            short8 a[4], b[4];
#pragma unroll
            for (int t = 0; t < 4; ++t) {
                int arow  = wm + t * 16 + lm;
                int aslot = ((kk >> 3) + q) ^ (arow & 7);
                a[t] = *(const short8*)(As + arow * 64 + aslot * 8);
                int brow  = wn + t * 16 + lm;
                int bslot = ((kk >> 3) + q) ^ (brow & 7);
                b[t] = *(const short8*)(Bs + brow * 64 + bslot * 8);
            }
#pragma unroll
            for (int um = 0; um < 4; ++um)
#pragma unroll
                for (int un = 0; un < 4; ++un)
                    acc[um][un] = __builtin_amdgcn_mfma_f32_16x16x32_bf16(a[um], b[un], acc[um][un], 0, 0, 0);
        }
    }
}

// 64x64-tile variant (for gemm_H: high block count -> occupancy)
__device__ __forceinline__ void mfma_gemm_64(const unsigned short* __restrict__ Ag, long astride,
                                             const unsigned short* __restrict__ Bg, long bstride,
                                             int kiters,
                                             unsigned short* As, unsigned short* Bs,
                                             f32x4 acc[2][2])
{
    const int tid  = threadIdx.x;
    const int wave = tid >> 6, lane = tid & 63;
    const int q    = lane >> 4, lm = lane & 15;
    const int wm   = (wave >> 1) * 32, wn = (wave & 1) * 32;
    const int crow = lane >> 3;
    const int gcol = ((lane & 7) ^ crow) * 8;

    for (int kt = 0; kt < kiters; ++kt) {
        const long k0 = (long)kt * 64;
        __syncthreads();
#pragma unroll
        for (int i2 = 0; i2 < 2; ++i2) {
            int c   = i2 * 4 + wave;                  // chunk 0..7
            int row = c * 8 + crow;                   // 0..63
            const unsigned short* ga = Ag + (long)row * astride + k0 + gcol;
            const unsigned short* gb = Bg + (long)row * bstride + k0 + gcol;
            __builtin_amdgcn_global_load_lds((const __attribute__((address_space(1))) void*)ga,
                                             (__attribute__((address_space(3))) void*)(As + c * 512),
                                             16, 0, 0);
            __builtin_amdgcn_global_load_lds((const __attribute__((address_space(1))) void*)gb,
                                             (__attribute__((address_space(3))) void*)(Bs + c * 512),
                                             16, 0, 0);
        }
        __syncthreads();
#pragma unroll
        for (int kk = 0; kk < 64; kk += 32) {
            short8 a[2], b[2];
#pragma unroll
            for (int t = 0; t < 2; ++t) {
                int arow  = wm + t * 16 + lm;
                int aslot = ((kk >> 3) + q) ^ (arow & 7);
                a[t] = *(const short8*)(As + arow * 64 + aslot * 8);
                int brow  = wn + t * 16 + lm;
                int bslot = ((kk >> 3) + q) ^ (brow & 7);
                b[t] = *(const short8*)(Bs + brow * 64 + bslot * 8);
            }
#pragma unroll
            for (int um = 0; um < 2; ++um)
#pragma unroll
                for (int un = 0; un < 2; ++un)
                    acc[um][un] = __builtin_amdgcn_mfma_f32_16x16x32_bf16(a[um], b[un], acc[um][un], 0, 0, 0);
        }
    }
}

// ---------------------------------------------------------------------------
// Main mixing GEMM: bd2 = A2 @ (B2 - I)  (branch_delta directly, no psi read).
// Epilogue stores bf16 bd2 and accumulates sum(bd^2) into scal[l].
// ---------------------------------------------------------------------------
__global__ __launch_bounds__(256) void gemm_main(const unsigned short* __restrict__ A2,
                                                 const unsigned short* __restrict__ B2T,
                                                 unsigned short* __restrict__ bd2,
                                                 float* __restrict__ scal, int l)
{
    __shared__ unsigned short As[128 * 64];
    __shared__ unsigned short Bs[128 * 64];
    __shared__ float red[4];
    f32x4 acc[4][4];
#pragma unroll
    for (int i = 0; i < 4; ++i)
#pragma unroll
        for (int j = 0; j < 4; ++j) acc[i][j] = (f32x4)0.0f;

    const int nt = blockIdx.x, mt = blockIdx.y;
    mfma_gemm_128(A2 + (long)mt * 128 * K2_, K2_,
                  B2T + (long)nt * 128 * K2_, K2_, K2_ / 64, As, Bs, acc);

    const int tid = threadIdx.x, wave = tid >> 6, lane = tid & 63;
    const int q = lane >> 4, lm = lane & 15;
    const int wm = (wave >> 1) * 64, wn = (wave & 1) * 64;
    float ss = 0.f;
#pragma unroll
    for (int um = 0; um < 4; ++um) {
#pragma unroll
        for (int un = 0; un < 4; ++un) {
            int coln = nt * 128 + wn + un * 16 + lm;
#pragma unroll
            for (int i = 0; i < 4; ++i) {
                int rowm = mt * 128 + wm + um * 16 + q * 4 + i;
                float bd = acc[um][un][i];
                bd2[(long)rowm * N2_ + coln] = f2bf(bd);
                ss += bd * bd;
            }
        }
    }
    for (int off = 32; off > 0; off >>= 1) ss += __shfl_down(ss, off);
    if (lane == 0) red[wave] = ss;
    __syncthreads();
    if (tid == 0) atomicAdd(scal + l, red[0] + red[1] + red[2] + red[3]);
}

// ---------------------------------------------------------------------------
// H GEMM (64x64 tiles): H[b][d][e] = (1/S) sum_s magT[d,s] magT[e,s].
// Epilogue fuses ||H-Hp||^2, ||Hp||^2, diag max/min (atomics into scal).
// Layer 1 runs in place (Hp == H): each element is read before written by
// the single block that owns it.
// ---------------------------------------------------------------------------
__global__ __launch_bounds__(256) void gemm_H(const unsigned short* __restrict__ magT,
                                              const float* __restrict__ Hp,
                                              float* __restrict__ H,
                                              float* __restrict__ scal, int l)
{
    __shared__ unsigned short As[64 * 64];
    __shared__ unsigned short Bs[64 * 64];
    __shared__ float redd[4], redp[4];
    f32x4 acc[2][2];
#pragma unroll
    for (int i = 0; i < 2; ++i)
#pragma unroll
        for (int j = 0; j < 2; ++j) acc[i][j] = (f32x4)0.0f;

    const int b = blockIdx.z;
    const unsigned short* Mb = magT + (long)b * D_ * S_;
    mfma_gemm_64(Mb + (long)blockIdx.y * 64 * S_, S_,
                 Mb + (long)blockIdx.x * 64 * S_, S_, S_ / 64, As, Bs, acc);

    const int tid = threadIdx.x, wave = tid >> 6, lane = tid & 63;
    const int q = lane >> 4, lm = lane & 15;
    const int wm = (wave >> 1) * 32, wn = (wave & 1) * 32;
    const float inv_s = 1.0f / (float)S_;
    float d2 = 0.f, p2 = 0.f;
#pragma unroll
    for (int um = 0; um < 2; ++um) {
#pragma unroll
        for (int un = 0; un < 2; ++un) {
            int coln = blockIdx.x * 64 + wn + un * 16 + lm;
#pragma unroll
            for (int i = 0; i < 4; ++i) {
                int rowm = blockIdx.y * 64 + wm + um * 16 + q * 4 + i;
                long adr = (long)b * DD + (long)rowm * D_ + coln;
                float hp = Hp[adr];
                float h  = acc[um][un][i] * inv_s;
                H[adr] = h;
                float df = h - hp;
                d2 += df * df;
                p2 += hp * hp;
                if (rowm == coln) {
                    atomicMax((int*)scal + 18 + l * 4 + b, __float_as_int(h));
                    atomicMin((int*)scal + 26 + l * 4 + b, __float_as_int(h));
                }
            }
        }
    }
    for (int off = 32; off > 0; off >>= 1) { d2 += __shfl_down(d2, off); p2 += __shfl_down(p2, off); }
    if (lane == 0) { redd[wave] = d2; redp[wave] = p2; }
    __syncthreads();
    if (tid == 0) {
        atomicAdd(scal + 2 + l * 4 + b,  redd[0] + redd[1] + redd[2] + redd[3]);
        atomicAdd(scal + 10 + l * 4 + b, redp[0] + redp[1] + redp[2] + redp[3]);
    }
}

// psi <- x (fp32 residual in d_out), A2 <- bf16 pack [psi_r | psi_i]; block 0
// also initializes the scalar slots (workspace is poisoned each call).
__global__ void init_kernel(const float* __restrict__ xr, const float* __restrict__ xi,
                            float* __restrict__ psi_r, float* __restrict__ psi_i,
                            unsigned short* __restrict__ A2, float* __restrict__ scal)
{
    if (blockIdx.x == 0 && threadIdx.x < 34)
        scal[threadIdx.x] = (threadIdx.x >= 26) ? 3.402823466e38f : 0.0f;
    long t = (long)blockIdx.x * 256 + threadIdx.x;
    long i = t * 4;
    f32x4 r  = *(const f32x4*)(xr + i);
    f32x4 im = *(const f32x4*)(xi + i);
    *(f32x4*)(psi_r + i) = r;
    *(f32x4*)(psi_i + i) = im;
    long m = i / D_; int d = (int)(i % D_);
    u16x4 rr, ii;
#pragma unroll
    for (int j = 0; j < 4; ++j) { rr[j] = f2bf(r[j]); ii[j] = f2bf(im[j]); }
    *(u16x4*)(A2 + m * K2_ + d) = rr;
    *(u16x4*)(A2 + m * K2_ + D_ + d) = ii;
}

// B2T[l][n][k] = (B2 - I)[k][n], B2 = [[Wr, Wi], [-Wi, Wr]]; both layers.
__global__ __launch_bounds__(256) void pack_b2t(const float* __restrict__ Wr_all,
                                                const float* __restrict__ Wi_all,
                                                unsigned short* __restrict__ B2T_all)
{
    __shared__ float T[64][65];
    const int l = blockIdx.z;
    const float* Wr = Wr_all + (long)l * DD;
    const float* Wi = Wi_all + (long)l * DD;
    unsigned short* B2T = B2T_all + (long)l * N2_ * K2_;
    int k0 = blockIdx.x * 64;
    int n0 = blockIdx.y * 64;
    int t = threadIdx.x;
#pragma unroll
    for (int it = 0; it < 16; ++it) {
        int idx = it * 256 + t;
        int kl = idx >> 6, nl = idx & 63;
        int k = k0 + kl, n = n0 + nl;
        float v;
        if (k < D_) v = (n < D_) ? Wr[k * D_ + n] : Wi[k * D_ + (n - D_)];
        else        v = (n < D_) ? -Wi[(k - D_) * D_ + n] : Wr[(k - D_) * D_ + (n - D_)];
        if (k == n) v -= 1.0f;     // fold -I: GEMM emits branch_delta directly
        T[kl][nl] = v;
    }
    __syncthreads();
#pragma unroll
    for (int it = 0; it < 16; ++it) {
        int idx = it * 256 + t;
        int nl = idx >> 6, kl = idx & 63;
        B2T[(long)(n0 + nl) * K2_ + (k0 + kl)] = f2bf(T[kl][nl]);
    }
}

// dampv[l][d] = 1 - gamma * sum_k L[l][k][d]^2, both layers (grid 8)
__global__ void damp_kernel(const float* __restrict__ Lops, float* __restrict__ dampv)
{
    int g = blockIdx.x;
    int l = g >> 2;
    int d = (g & 3) * 256 + threadIdx.x;
    const float* Lp = Lops + (long)l * 4 * D_;
    float s = 0.f;
#pragma unroll
    for (int k = 0; k < 4; ++k) { float v = Lp[k * D_ + d]; s += v * v; }
    dampv[l * D_ + d] = 1.0f - 0.01f * s;
}

// magT[b][d][s] = |bd[b,s,d]| * dampv[d] / rms   (rms computed inline)
__global__ __launch_bounds__(256) void magt_kernel(const unsigned short* __restrict__ bd2,
                                                   const float* __restrict__ dampv,
                                                   const float* __restrict__ scal, int l,
                                                   unsigned short* __restrict__ magT)
{
    __shared__ float T[64][65];
    float mean = fmaxf(scal[l] / (float)NTOT, 1e-12f);
    const float inv = 1.0f / fmaxf(sqrtf(mean), 1e-3f);
    int m0 = blockIdx.x * 64;
    int d0 = blockIdx.y * 64;
    int t = threadIdx.x;
#pragma unroll
    for (int it = 0; it < 16; ++it) {
        int idx = it * 256 + t;
        int sl = idx >> 6, dl = idx & 63;
        long m = m0 + sl; int d = d0 + dl;
        float br = bf2f(bd2[m * N2_ + d]);
        float bi = bf2f(bd2[m * N2_ + D_ + d]);
        T[sl][dl] = sqrtf(br * br + bi * bi) * dampv[d] * inv;
    }
    __syncthreads();
    int b = m0 / S_;
    int s0 = m0 % S_;
#pragma unroll
    for (int it = 0; it < 16; ++it) {
        int idx = it * 256 + t;
        int dl = idx >> 6, sl = idx & 63;
        magT[(long)b * D_ * S_ + (long)(d0 + dl) * S_ + (s0 + sl)] = f2bf(T[sl][dl]);
    }
}

// psi += bd*(1-damp)*factor (complex); factors computed inline from scalars;
// optionally re-pack A2 for next layer.
__global__ void update_kernel(const unsigned short* __restrict__ bd2,
                              const float* __restrict__ dampv,
                              const float* __restrict__ scal,
                              const float* __restrict__ theta,
                              const float* __restrict__ jscale,
                              const float* __restrict__ kappa, int l,
                              float* __restrict__ psi_r,
                              float* __restrict__ psi_i,
                              unsigned short* __restrict__ A2,
                              int write_a2)
{
    long t = (long)blockIdx.x * 256 + threadIdx.x;
    long i = t * 4;
    long m = i / D_; int d = (int)(i % D_);
    int b = (int)(m >> 11);           // m / S_

    float dn = sqrtf(scal[2 + l * 4 + b]);
    float pn = sqrtf(scal[10 + l * 4 + b]);
    float K  = dn / (pn + 1e-6f);
    float mx = __int_as_float(((const int*)scal)[18 + l * 4 + b]);
    float mn = __int_as_float(((const int*)scal)[26 + l * 4 + b]);
    int jumped  = K > kappa[l];
    int escaped = (mx / (mn + 1e-12f)) > 100.0f;
    float js = jumped ? jscale[l] : 1.0f;
    float th = theta[l];
    float fr = js * (escaped ? cosf(th) : 1.0f);
    float fi = js * (escaped ? sinf(th) : 0.0f);

    u16x4 brv = *(const u16x4*)(bd2 + m * N2_ + d);
    u16x4 biv = *(const u16x4*)(bd2 + m * N2_ + D_ + d);
    f32x4 w  = *(const f32x4*)(dampv + d);
    f32x4 pr = *(const f32x4*)(psi_r + i);
    f32x4 pi = *(const f32x4*)(psi_i + i);
    u16x4 ar, ai;
#pragma unroll
    for (int j = 0; j < 4; ++j) {
        float br = bf2f(brv[j]) * w[j];
        float bi = bf2f(biv[j]) * w[j];
        float nr = pr[j] + br * fr - bi * fi;
        float ni = pi[j] + br * fi + bi * fr;
        pr[j] = nr; pi[j] = ni;
        ar[j] = f2bf(nr); ai[j] = f2bf(ni);
    }
    *(f32x4*)(psi_r + i) = pr;
    *(f32x4*)(psi_i + i) = pi;
    if (write_a2) {
        *(u16x4*)(A2 + m * K2_ + d) = ar;
        *(u16x4*)(A2 + m * K2_ + D_ + d) = ai;
    }
}

extern "C" void kernel_launch(void* const* d_in, const int* in_sizes, int n_in,
                              void* d_out, int out_size, void* d_ws, size_t ws_size,
                              hipStream_t stream)
{
    const float* xr     = (const float*)d_in[0];
    const float* xi     = (const float*)d_in[1];
    const float* Hprev  = (const float*)d_in[2];
    const float* Wr     = (const float*)d_in[3];
    const float* Wi     = (const float*)d_in[4];
    const float* Lops   = (const float*)d_in[5];
    const float* theta  = (const float*)d_in[6];
    const float* jscale = (const float*)d_in[7];
    const float* kappa  = (const float*)d_in[8];

    float* psi_r = (float*)d_out;           // [B,S,D] real plane
    float* psi_i = psi_r + NTOT;            // imag plane

    char* ws = (char*)d_ws;
    unsigned short* A2   = (unsigned short*)ws;               // 32 MiB
    unsigned short* magT = A2;                                // aliased (A2 dead while magT live)
    unsigned short* B2T  = (unsigned short*)(ws + 33554432);  // 16 MiB (both layers)
    unsigned short* bd2  = (unsigned short*)(ws + 50331648);  // 32 MiB
    float* H             = (float*)(ws + 83886080);           // 16 MiB (in-place across layers)
    float* scal          = (float*)(ws + 100663296);          // scalars + dampv
    float* dampv         = scal + 64;                         // [2][1024]

    init_kernel<<<NTOT / 4 / 256, 256, 0, stream>>>(xr, xi, psi_r, psi_i, A2, scal);
    damp_kernel<<<8, 256, 0, stream>>>(Lops, dampv);
    pack_b2t<<<dim3(32, 32, 2), 256, 0, stream>>>(Wr, Wi, B2T);

    for (int l = 0; l < 2; ++l) {
        const float* Hp = (l == 0) ? Hprev : H;
        gemm_main<<<dim3(N2_ / 128, M_ / 128), 256, 0, stream>>>(
            A2, B2T + (long)l * N2_ * K2_, bd2, scal, l);
        magt_kernel<<<dim3(M_ / 64, D_ / 64), 256, 0, stream>>>(
            bd2, dampv + l * D_, scal, l, magT);
        gemm_H<<<dim3(D_ / 64, D_ / 64, B_), 256, 0, stream>>>(magT, Hp, H, scal, l);
        update_kernel<<<NTOT / 4 / 256, 256, 0, stream>>>(
            bd2, dampv + l * D_, scal, theta, jscale, kappa, l,
            psi_r, psi_i, A2, l == 0);
    }
}

// Round 3
// 457.453 us; speedup vs baseline: 1.7012x; 1.1155x over previous
//
#include <hip/hip_runtime.h>

#define B_ 4
#define S_ 2048
#define D_ 1024
#define M_ (B_*S_)           // 8192
#define K2_ 2048
#define N2_ 2048
#define NTOT (B_*S_*D_)      // 8388608
#define DD (D_*D_)           // 1048576

typedef __attribute__((ext_vector_type(4))) float f32x4;
typedef __attribute__((ext_vector_type(8))) short short8;
typedef __attribute__((ext_vector_type(4))) unsigned short u16x4;
typedef __attribute__((ext_vector_type(8))) unsigned short u16x8;

static __device__ __forceinline__ unsigned short f2bf(float f) {
    union { float f; unsigned int u; } v; v.f = f;
    unsigned int u = v.u;
    unsigned int r = (u + 0x7fffu + ((u >> 16) & 1u)) >> 16;
    return (unsigned short)r;
}
static __device__ __forceinline__ float bf2f(unsigned short h) {
    union { unsigned int u; float f; } v; v.u = ((unsigned int)h) << 16;
    return v.f;
}

// scal layout (fp32 slots): [0..1] sumsq[l], [2..9] diff2[l*4+b],
// [10..17] prev2[l*4+b], [18..25] diag-max bits, [26..33] diag-min bits,
// [64..2111] dampv[2][1024]

// ---------------------------------------------------------------------------
// gemm_main2: paired-tile mixing GEMM. Block (nt, mt) computes BOTH the real
// column tile (cols nt*128..) and the imag tile (cols nt*128+1024..) against
// one A tile (128 rows). Emits: bd2 (bf16, [m][2048]), raw |bd| transposed
// into magT[b][d][s] (bf16, coalesced via LDS), and sum(bd^2) atomics.
// XOR-swizzled LDS staging (round-2 verified: 0 bank conflicts).
// ---------------------------------------------------------------------------
__global__ __launch_bounds__(256, 2) void gemm_main2(const unsigned short* __restrict__ A2,
                                                     const unsigned short* __restrict__ B2T,
                                                     unsigned short* __restrict__ bd2,
                                                     unsigned short* __restrict__ magT,
                                                     float* __restrict__ scal, int l)
{
    __shared__ unsigned short smem[3 * 128 * 64];   // 48 KB: As | Bsr | Bsi
    __shared__ float red[4];
    unsigned short* As  = smem;
    unsigned short* Bsr = smem + 8192;
    unsigned short* Bsi = smem + 16384;

    f32x4 accr[4][4], acci[4][4];
#pragma unroll
    for (int i = 0; i < 4; ++i)
#pragma unroll
        for (int j = 0; j < 4; ++j) { accr[i][j] = (f32x4)0.0f; acci[i][j] = (f32x4)0.0f; }

    const int nt = blockIdx.x, mt = blockIdx.y;
    const int tid = threadIdx.x, wave = tid >> 6, lane = tid & 63;
    const int q = lane >> 4, lm = lane & 15;
    const int wm = (wave >> 1) * 64, wn = (wave & 1) * 64;
    const int crow = lane >> 3;
    const int gcol = ((lane & 7) ^ crow) * 8;

    const unsigned short* Ag  = A2  + (long)mt * 128 * K2_;
    const unsigned short* Bgr = B2T + (long)(nt * 128) * K2_;
    const unsigned short* Bgi = B2T + (long)(nt * 128 + 1024) * K2_;

    for (int kt = 0; kt < K2_ / 64; ++kt) {
        const long k0 = (long)kt * 64;
        __syncthreads();
#pragma unroll
        for (int i2 = 0; i2 < 4; ++i2) {
            int c   = i2 * 4 + wave;
            int row = c * 8 + crow;
            long go = (long)row * K2_ + k0 + gcol;
            __builtin_amdgcn_global_load_lds((const __attribute__((address_space(1))) void*)(Ag + go),
                                             (__attribute__((address_space(3))) void*)(As + c * 512), 16, 0, 0);
            __builtin_amdgcn_global_load_lds((const __attribute__((address_space(1))) void*)(Bgr + go),
                                             (__attribute__((address_space(3))) void*)(Bsr + c * 512), 16, 0, 0);
            __builtin_amdgcn_global_load_lds((const __attribute__((address_space(1))) void*)(Bgi + go),
                                             (__attribute__((address_space(3))) void*)(Bsi + c * 512), 16, 0, 0);
        }
        __syncthreads();
#pragma unroll
        for (int kk = 0; kk < 64; kk += 32) {
            short8 a[4], br[4], bi[4];
#pragma unroll
            for (int t = 0; t < 4; ++t) {
                int arow  = wm + t * 16 + lm;
                int aslot = ((kk >> 3) + q) ^ (arow & 7);
                a[t] = *(const short8*)(As + arow * 64 + aslot * 8);
                int brow  = wn + t * 16 + lm;
                int bslot = ((kk >> 3) + q) ^ (brow & 7);
                br[t] = *(const short8*)(Bsr + brow * 64 + bslot * 8);
                bi[t] = *(const short8*)(Bsi + brow * 64 + bslot * 8);
            }
#pragma unroll
            for (int um = 0; um < 4; ++um)
#pragma unroll
                for (int un = 0; un < 4; ++un) {
                    accr[um][un] = __builtin_amdgcn_mfma_f32_16x16x32_bf16(a[um], br[un], accr[um][un], 0, 0, 0);
                    acci[um][un] = __builtin_amdgcn_mfma_f32_16x16x32_bf16(a[um], bi[un], acci[um][un], 0, 0, 0);
                }
        }
    }

    // --- epilogue: bd2 stores, sumsq, |bd| -> LDS (transposed) -------------
    __syncthreads();                     // all waves done reading smem frags
    unsigned short* magLds = smem;       // [128 d][136 stride] bf16 = 34816 B
    float ss = 0.f;
#pragma unroll
    for (int um = 0; um < 4; ++um) {
#pragma unroll
        for (int un = 0; un < 4; ++un) {
            int colb = wn + un * 16 + lm;          // block-local d 0..127
            int coln = nt * 128 + colb;
            u16x4 magv;
#pragma unroll
            for (int i = 0; i < 4; ++i) {
                long rowm = (long)mt * 128 + wm + um * 16 + q * 4 + i;
                float vr = accr[um][un][i];
                float vi = acci[um][un][i];
                bd2[rowm * N2_ + coln]        = f2bf(vr);
                bd2[rowm * N2_ + 1024 + coln] = f2bf(vi);
                float s2 = vr * vr + vi * vi;
                ss += s2;
                magv[i] = f2bf(sqrtf(s2));
            }
            *(u16x4*)(magLds + colb * 136 + wm + um * 16 + q * 4) = magv;
        }
    }
    for (int off = 32; off > 0; off >>= 1) ss += __shfl_down(ss, off);
    if (lane == 0) red[wave] = ss;
    __syncthreads();
    if (tid == 0) atomicAdd(scal + l, red[0] + red[1] + red[2] + red[3]);

    // --- coalesced magT writeout: magT[b][d][s], 256B runs per row ---------
    const int b   = mt >> 4;
    const long s0 = (long)(mt & 15) * 128;
#pragma unroll
    for (int it = 0; it < 8; ++it) {
        int sid = it * 256 + tid;
        int row = sid >> 4, seg = sid & 15;        // row: d-local, seg: 8-short chunk
        unsigned short* dst = magT + (long)b * D_ * S_ + (long)(nt * 128 + row) * S_ + s0 + seg * 8;
        *(u16x8*)dst = *(const u16x8*)(magLds + row * 136 + seg * 8);
    }
}

// 64x64-tile MFMA core (for gemm_H), XOR-swizzled LDS
__device__ __forceinline__ void mfma_gemm_64(const unsigned short* __restrict__ Ag, long astride,
                                             const unsigned short* __restrict__ Bg, long bstride,
                                             int kiters,
                                             unsigned short* As, unsigned short* Bs,
                                             f32x4 acc[2][2])
{
    const int tid  = threadIdx.x;
    const int wave = tid >> 6, lane = tid & 63;
    const int q    = lane >> 4, lm = lane & 15;
    const int wm   = (wave >> 1) * 32, wn = (wave & 1) * 32;
    const int crow = lane >> 3;
    const int gcol = ((lane & 7) ^ crow) * 8;

    for (int kt = 0; kt < kiters; ++kt) {
        const long k0 = (long)kt * 64;
        __syncthreads();
#pragma unroll
        for (int i2 = 0; i2 < 2; ++i2) {
            int c   = i2 * 4 + wave;
            int row = c * 8 + crow;
            const unsigned short* ga = Ag + (long)row * astride + k0 + gcol;
            const unsigned short* gb = Bg + (long)row * bstride + k0 + gcol;
            __builtin_amdgcn_global_load_lds((const __attribute__((address_space(1))) void*)ga,
                                             (__attribute__((address_space(3))) void*)(As + c * 512), 16, 0, 0);
            __builtin_amdgcn_global_load_lds((const __attribute__((address_space(1))) void*)gb,
                                             (__attribute__((address_space(3))) void*)(Bs + c * 512), 16, 0, 0);
        }
        __syncthreads();
#pragma unroll
        for (int kk = 0; kk < 64; kk += 32) {
            short8 a[2], b[2];
#pragma unroll
            for (int t = 0; t < 2; ++t) {
                int arow  = wm + t * 16 + lm;
                int aslot = ((kk >> 3) + q) ^ (arow & 7);
                a[t] = *(const short8*)(As + arow * 64 + aslot * 8);
                int brow  = wn + t * 16 + lm;
                int bslot = ((kk >> 3) + q) ^ (brow & 7);
                b[t] = *(const short8*)(Bs + brow * 64 + bslot * 8);
            }
#pragma unroll
            for (int um = 0; um < 2; ++um)
#pragma unroll
                for (int un = 0; un < 2; ++un)
                    acc[um][un] = __builtin_amdgcn_mfma_f32_16x16x32_bf16(a[um], b[un], acc[um][un], 0, 0, 0);
        }
    }
}

// ---------------------------------------------------------------------------
// gemm_H: symmetric Gram. Only upper-triangle tile pairs (136 per batch);
// off-diag blocks write H[d,e] AND H[e,d] and double-count norm terms.
// Scale damp[d]*damp[e]/(rms^2*S) folded here (magT holds raw |bd|).
// In-place across layers: each element owned by exactly one lane.
// ---------------------------------------------------------------------------
__global__ __launch_bounds__(256) void gemm_H(const unsigned short* __restrict__ magT,
                                              const float* __restrict__ Hp,
                                              float* __restrict__ H,
                                              float* __restrict__ scal,
                                              const float* __restrict__ dampv, int l)
{
    __shared__ unsigned short As[64 * 64];
    __shared__ unsigned short Bs[64 * 64];
    __shared__ float redd[4], redp[4];

    int idx = blockIdx.x, ty = 0;
    while (idx >= 16 - ty) { idx -= 16 - ty; ++ty; }
    const int tx = ty + idx;                 // tx >= ty
    const int b = blockIdx.y;
    const int diag = (tx == ty);

    f32x4 acc[2][2];
#pragma unroll
    for (int i = 0; i < 2; ++i)
#pragma unroll
        for (int j = 0; j < 2; ++j) acc[i][j] = (f32x4)0.0f;

    const unsigned short* Mb = magT + (long)b * D_ * S_;
    mfma_gemm_64(Mb + (long)ty * 64 * S_, S_,
                 Mb + (long)tx * 64 * S_, S_, S_ / 64, As, Bs, acc);

    float mean = fmaxf(scal[l] / (float)NTOT, 1e-12f);
    float inv  = 1.0f / fmaxf(sqrtf(mean), 1e-3f);
    const float scale = inv * inv / (float)S_;

    const int tid = threadIdx.x, wave = tid >> 6, lane = tid & 63;
    const int q = lane >> 4, lm = lane & 15;
    const int wm = (wave >> 1) * 32, wn = (wave & 1) * 32;
    float d2 = 0.f, p2 = 0.f;
#pragma unroll
    for (int um = 0; um < 2; ++um) {
#pragma unroll
        for (int un = 0; un < 2; ++un) {
            int coln = tx * 64 + wn + un * 16 + lm;
            float de = dampv[coln];
#pragma unroll
            for (int i = 0; i < 4; ++i) {
                int rowm = ty * 64 + wm + um * 16 + q * 4 + i;
                float h = acc[um][un][i] * scale * dampv[rowm] * de;
                long adr = (long)b * DD + (long)rowm * D_ + coln;
                float hp1 = Hp[adr];
                float df1 = h - hp1;
                if (diag) {
                    H[adr] = h;
                    d2 += df1 * df1;
                    p2 += hp1 * hp1;
                    if (rowm == coln) {
                        atomicMax((int*)scal + 18 + l * 4 + b, __float_as_int(h));
                        atomicMin((int*)scal + 26 + l * 4 + b, __float_as_int(h));
                    }
                } else {
                    long adrT = (long)b * DD + (long)coln * D_ + rowm;
                    float hp2 = Hp[adrT];
                    H[adr]  = h;
                    H[adrT] = h;
                    float df2 = h - hp2;
                    d2 += df1 * df1 + df2 * df2;
                    p2 += hp1 * hp1 + hp2 * hp2;
                }
            }
        }
    }
    for (int off = 32; off > 0; off >>= 1) { d2 += __shfl_down(d2, off); p2 += __shfl_down(p2, off); }
    if (lane == 0) { redd[wave] = d2; redp[wave] = p2; }
    __syncthreads();
    if (tid == 0) {
        atomicAdd(scal + 2 + l * 4 + b,  redd[0] + redd[1] + redd[2] + redd[3]);
        atomicAdd(scal + 10 + l * 4 + b, redp[0] + redp[1] + redp[2] + redp[3]);
    }
}

// psi <- x (fp32 residual in d_out), A2 <- bf16 pack; block 0 inits scalars.
__global__ void init_kernel(const float* __restrict__ xr, const float* __restrict__ xi,
                            float* __restrict__ psi_r, float* __restrict__ psi_i,
                            unsigned short* __restrict__ A2, float* __restrict__ scal)
{
    if (blockIdx.x == 0 && threadIdx.x < 34)
        scal[threadIdx.x] = (threadIdx.x >= 26) ? 3.402823466e38f : 0.0f;
    long t = (long)blockIdx.x * 256 + threadIdx.x;
    long i = t * 4;
    f32x4 r  = *(const f32x4*)(xr + i);
    f32x4 im = *(const f32x4*)(xi + i);
    *(f32x4*)(psi_r + i) = r;
    *(f32x4*)(psi_i + i) = im;
    long m = i / D_; int d = (int)(i % D_);
    u16x4 rr, ii;
#pragma unroll
    for (int j = 0; j < 4; ++j) { rr[j] = f2bf(r[j]); ii[j] = f2bf(im[j]); }
    *(u16x4*)(A2 + m * K2_ + d) = rr;
    *(u16x4*)(A2 + m * K2_ + D_ + d) = ii;
}

// B2T[n][k] = (B2 - I)[k][n] for layer l, B2 = [[Wr, Wi], [-Wi, Wr]]
__global__ __launch_bounds__(256) void pack_b2t(const float* __restrict__ Wr_all,
                                                const float* __restrict__ Wi_all,
                                                unsigned short* __restrict__ B2T, int l)
{
    __shared__ float T[64][65];
    const float* Wr = Wr_all + (long)l * DD;
    const float* Wi = Wi_all + (long)l * DD;
    int k0 = blockIdx.x * 64;
    int n0 = blockIdx.y * 64;
    int t = threadIdx.x;
#pragma unroll
    for (int it = 0; it < 16; ++it) {
        int idx = it * 256 + t;
        int kl = idx >> 6, nl = idx & 63;
        int k = k0 + kl, n = n0 + nl;
        float v;
        if (k < D_) v = (n < D_) ? Wr[k * D_ + n] : Wi[k * D_ + (n - D_)];
        else        v = (n < D_) ? -Wi[(k - D_) * D_ + n] : Wr[(k - D_) * D_ + (n - D_)];
        if (k == n) v -= 1.0f;     // fold -I: GEMM emits branch_delta directly
        T[kl][nl] = v;
    }
    __syncthreads();
#pragma unroll
    for (int it = 0; it < 16; ++it) {
        int idx = it * 256 + t;
        int nl = idx >> 6, kl = idx & 63;
        B2T[(long)(n0 + nl) * K2_ + (k0 + kl)] = f2bf(T[kl][nl]);
    }
}

// dampv[l][d] = 1 - gamma * sum_k L[l][k][d]^2, both layers
__global__ void damp_kernel(const float* __restrict__ Lops, float* __restrict__ dampv)
{
    int g = blockIdx.x;
    int l = g >> 2;
    int d = (g & 3) * 256 + threadIdx.x;
    const float* Lp = Lops + (long)l * 4 * D_;
    float s = 0.f;
#pragma unroll
    for (int k = 0; k < 4; ++k) { float v = Lp[k * D_ + d]; s += v * v; }
    dampv[l * D_ + d] = 1.0f - 0.01f * s;
}

// psi += bd*damp*factor (complex); factors computed inline; optional A2 repack
__global__ void update_kernel(const unsigned short* __restrict__ bd2,
                              const float* __restrict__ dampv,
                              const float* __restrict__ scal,
                              const float* __restrict__ theta,
                              const float* __restrict__ jscale,
                              const float* __restrict__ kappa, int l,
                              float* __restrict__ psi_r,
                              float* __restrict__ psi_i,
                              unsigned short* __restrict__ A2,
                              int write_a2)
{
    long t = (long)blockIdx.x * 256 + threadIdx.x;
    long i = t * 4;
    long m = i / D_; int d = (int)(i % D_);
    int b = (int)(m >> 11);           // m / S_

    float dn = sqrtf(scal[2 + l * 4 + b]);
    float pn = sqrtf(scal[10 + l * 4 + b]);
    float K  = dn / (pn + 1e-6f);
    float mx = __int_as_float(((const int*)scal)[18 + l * 4 + b]);
    float mn = __int_as_float(((const int*)scal)[26 + l * 4 + b]);
    int jumped  = K > kappa[l];
    int escaped = (mx / (mn + 1e-12f)) > 100.0f;
    float js = jumped ? jscale[l] : 1.0f;
    float th = theta[l];
    float fr = js * (escaped ? cosf(th) : 1.0f);
    float fi = js * (escaped ? sinf(th) : 0.0f);

    u16x4 brv = *(const u16x4*)(bd2 + m * N2_ + d);
    u16x4 biv = *(const u16x4*)(bd2 + m * N2_ + D_ + d);
    f32x4 w  = *(const f32x4*)(dampv + d);
    f32x4 pr = *(const f32x4*)(psi_r + i);
    f32x4 pi = *(const f32x4*)(psi_i + i);
    u16x4 ar, ai;
#pragma unroll
    for (int j = 0; j < 4; ++j) {
        float br = bf2f(brv[j]) * w[j];
        float bi = bf2f(biv[j]) * w[j];
        float nr = pr[j] + br * fr - bi * fi;
        float ni = pi[j] + br * fi + bi * fr;
        pr[j] = nr; pi[j] = ni;
        ar[j] = f2bf(nr); ai[j] = f2bf(ni);
    }
    *(f32x4*)(psi_r + i) = pr;
    *(f32x4*)(psi_i + i) = pi;
    if (write_a2) {
        *(u16x4*)(A2 + m * K2_ + d) = ar;
        *(u16x4*)(A2 + m * K2_ + D_ + d) = ai;
    }
}

extern "C" void kernel_launch(void* const* d_in, const int* in_sizes, int n_in,
                              void* d_out, int out_size, void* d_ws, size_t ws_size,
                              hipStream_t stream)
{
    const float* xr     = (const float*)d_in[0];
    const float* xi     = (const float*)d_in[1];
    const float* Hprev  = (const float*)d_in[2];
    const float* Wr     = (const float*)d_in[3];
    const float* Wi     = (const float*)d_in[4];
    const float* Lops   = (const float*)d_in[5];
    const float* theta  = (const float*)d_in[6];
    const float* jscale = (const float*)d_in[7];
    const float* kappa  = (const float*)d_in[8];

    float* psi_r = (float*)d_out;           // [B,S,D] real plane
    float* psi_i = psi_r + NTOT;            // imag plane

    char* ws = (char*)d_ws;
    unsigned short* A2   = (unsigned short*)ws;               // 32 MiB
    unsigned short* B2T  = (unsigned short*)(ws + 33554432);  //  8 MiB (per-layer)
    unsigned short* bd2  = (unsigned short*)(ws + 41943040);  // 32 MiB
    unsigned short* magT = (unsigned short*)(ws + 75497472);  // 16 MiB
    float* H             = (float*)(ws + 92274688);           // 16 MiB (in-place)
    float* scal          = (float*)(ws + 109051904);          // scalars + dampv
    float* dampv         = scal + 64;                         // [2][1024]

    init_kernel<<<NTOT / 4 / 256, 256, 0, stream>>>(xr, xi, psi_r, psi_i, A2, scal);
    damp_kernel<<<8, 256, 0, stream>>>(Lops, dampv);

    for (int l = 0; l < 2; ++l) {
        const float* Hp = (l == 0) ? Hprev : H;
        pack_b2t<<<dim3(32, 32), 256, 0, stream>>>(Wr, Wi, B2T, l);
        gemm_main2<<<dim3(8, M_ / 128), 256, 0, stream>>>(A2, B2T, bd2, magT, scal, l);
        gemm_H<<<dim3(136, B_), 256, 0, stream>>>(magT, Hp, H, scal, dampv + l * D_, l);
        update_kernel<<<NTOT / 4 / 256, 256, 0, stream>>>(
            bd2, dampv + l * D_, scal, theta, jscale, kappa, l,
            psi_r, psi_i, A2, l == 0);
    }
}